// Round 8
// baseline (221.894 us; speedup 1.0000x reference)
//
#include <hip/hip_runtime.h>
#include <math.h>

// Problem constants (B=4, C=64, H=W=192, K=3)
constexpr int Hh  = 192;
constexpr int Ww  = 192;
constexpr int HWp = Hh * Ww;      // 36864
constexpr int Cc  = 64;
constexpr int Bb  = 4;
constexpr int KK  = 9;
constexpr int OFFC = 18;          // 2*K*K
constexpr int PXB = 32;           // pixels per fused block (divides Ww)
constexpr int NBPX = HWp / PXB;   // 1152 tiles per batch image
constexpr int KSD = (Cc * KK) / 32;  // 18 K-steps, K=576
constexpr int KSC = Cc / 32;         // 2  K-steps, K=64
constexpr int NIT = KK * PXB;        // 288 (tap,pixel) items per block
constexpr int SLOTS = 64;            // stats accumulation slots per channel

constexpr int NXP = Bb * (HWp / 64);                                 // 2304 xpose blocks
constexpr int NWP = (4 * KSD * 64 * 8 + 4 * KSC * 64 * 8 + 2 * KSD * 64 * 8) / 256;  // 232
constexpr int NZP = (2 * Cc * SLOTS / 4) / 256;                      // 8 psum-zero blocks

using bf16x8 = __attribute__((ext_vector_type(8))) short;  // 8 bf16 (4 VGPRs)
using f32x4  = __attribute__((ext_vector_type(4))) float;

static __device__ __forceinline__ unsigned short f2bf(float f) {
    unsigned int u = __float_as_uint(f);
    u += 0x7fff + ((u >> 16) & 1);       // round-to-nearest-even
    return (unsigned short)(u >> 16);
}
static __device__ __forceinline__ float bf2f(unsigned short u) {
    return __uint_as_float((unsigned)u << 16);
}

// ---------------- Kernel 1: prep = {x transpose to CL bf16 | weight packing | psum zero} --------
// B-frag (16x16x32): lane l, reg r holds B[k = ks*32 + (l>>4)*8 + r][n = ot*16 + (l&15)]
// Deform/offset K-ordering is kk-major: ck2 = kk*64 + c (matches samp tile layout).
__global__ __launch_bounds__(256)
void k_prep(const float* __restrict__ x, const float* __restrict__ Wdef,
            const float* __restrict__ Wcat, const float* __restrict__ Woff,
            unsigned short* __restrict__ xcl, unsigned short* __restrict__ Fd,
            unsigned short* __restrict__ Fc, unsigned short* __restrict__ Fo,
            float* __restrict__ psum) {
    __shared__ unsigned short tile[64][66];
    const int bid = blockIdx.x;
    const int t = threadIdx.x;
    if (bid < NXP) {
        // ---- x NCHW f32 -> channels-last bf16 [B][HW][64c]
        int b   = bid / (HWp / 64);
        int px0 = (bid % (HWp / 64)) * 64;
        #pragma unroll
        for (int r = 0; r < 4; ++r) {                  // load: float4 per thread
            int c = r * 16 + (t >> 4), px4 = (t & 15) * 4;
            float4 v = *(const float4*)(x + ((size_t)b * Cc + c) * HWp + px0 + px4);
            tile[c][px4 + 0] = f2bf(v.x);
            tile[c][px4 + 1] = f2bf(v.y);
            tile[c][px4 + 2] = f2bf(v.z);
            tile[c][px4 + 3] = f2bf(v.w);
        }
        __syncthreads();
        #pragma unroll
        for (int r = 0; r < 4; ++r) {                  // store: ushort4 per thread
            int pxl = r * 16 + (t >> 4), c4 = (t & 15) * 4;
            ushort4 u;
            u.x = tile[c4 + 0][pxl];
            u.y = tile[c4 + 1][pxl];
            u.z = tile[c4 + 2][pxl];
            u.w = tile[c4 + 3][pxl];
            *(ushort4*)(xcl + ((size_t)b * HWp + px0 + pxl) * Cc + c4) = u;
        }
    } else if (bid < NXP + NWP) {
        int i = (bid - NXP) * 256 + t;
        if (i < 4 * KSD * 64 * 8) {                    // Fd: [ot4][ks18][lane][r]
            int r = i & 7, lane = (i >> 3) & 63, ks = (i >> 9) % KSD, ot = (i >> 9) / KSD;
            int o  = ot * 16 + (lane & 15);
            int kp = ks * 32 + ((lane >> 4) << 3) + r; // ck2 = kk*64 + c
            int kk = kp >> 6, c = kp & 63;
            Fd[i] = f2bf(Wdef[o * (Cc * KK) + c * KK + kk]);
        }
        int j = i - 4 * KSD * 64 * 8;
        if (j >= 0 && j < 4 * KSC * 64 * 8) {          // Fc: [ot4][ks2][lane][r]  (K = c)
            int r = j & 7, lane = (j >> 3) & 63, ks = (j >> 9) & 1, ot = j >> 10;
            int o = ot * 16 + (lane & 15);
            int c = ks * 32 + ((lane >> 4) << 3) + r;
            Fc[j] = f2bf(Wcat[o * Cc + c]);
        }
        int m = j - 4 * KSC * 64 * 8;
        if (m >= 0 && m < 2 * KSD * 64 * 8) {          // Fo: [ot2][ks18][lane][r], oc>=18 zero
            int r = m & 7, lane = (m >> 3) & 63, ks = (m >> 9) % KSD, ot = (m >> 9) / KSD;
            int o  = ot * 16 + (lane & 15);
            int kp = ks * 32 + ((lane >> 4) << 3) + r;
            int kk = kp >> 6, c = kp & 63;
            Fo[m] = (o < OFFC) ? f2bf(Woff[o * (Cc * KK) + c * KK + kk]) : 0;
        }
    } else {
        int j = (bid - NXP - NWP) * 256 + t;           // zero psum: 2048 float4
        float4 z = {0.f, 0.f, 0.f, 0.f};
        ((float4*)psum)[j] = z;
    }
}

// ---------------- Kernel 2: FUSED offset-conv + deformable conv + 1x1 conv + BN partials --------
// 512 threads (8 waves), 3 blocks/CU (LDS-limited) -> 24 waves/CU.
__global__ __launch_bounds__(512)
void k_fused(const unsigned short* __restrict__ xcl,
             const unsigned short* __restrict__ Fo, const float* __restrict__ boff,
             const unsigned short* __restrict__ Fd, const float* __restrict__ bdef,
             const unsigned short* __restrict__ Fc, const float* __restrict__ bcat,
             unsigned short* __restrict__ y, float* __restrict__ psum) {
    // s_buf: bf16 [32 px][576 ck2] swizzled (ck2 = kk*64+c); aliased fp32[64 o][32 px] in epilogue
    __shared__ __align__(16) unsigned char s_buf[PXB * Cc * KK * 2];   // 36864 B
    __shared__ __align__(16) unsigned char s_y1[PXB * Cc * 2];         // 4096 B
    __shared__ float s_off[PXB][OFFC];                                 // 2304 B
    __shared__ __align__(16) int s_pp[NIT * 8];                        // 9216 B

    const int t = threadIdx.x;
    const int lane = t & 63, wv = t >> 6;          // 8 waves
    const int klane = (lane >> 4) & 3;
    const int c4 = (lane & 15) * 4;
    int wg = blockIdx.x;
    const int slot = wg & (SLOTS - 1);
    wg = (wg & 7) * (Bb * NBPX / 8) + (wg >> 3);   // XCD swizzle (4608 % 8 == 0 -> bijective)
    const int b   = wg / NBPX;
    const int px0 = (wg % NBPX) * PXB;
    const int h   = px0 / Ww;                      // uniform: PXB divides Ww
    const int w0  = px0 % Ww;
    const unsigned short* xb = xcl + (size_t)b * HWp * Cc;

    // ---- P0: plain 3x3 taps (zero-padded) -> s_buf; 32 items/round x 9 rounds
    #pragma unroll
    for (int it = 0; it < NIT / 32; ++it) {
        int item = it * 32 + wv * 4 + klane;       // 0..287
        int kk = item >> 5, pxl = item & 31;
        int ky = (kk * 11) >> 5, kx = kk - ky * 3;
        int row = h + ky - 1;
        int col = w0 + pxl + kx - 1;
        ushort4 u = {0, 0, 0, 0};
        if (row >= 0 && row < Hh && col >= 0 && col < Ww)
            u = *(const ushort4*)(xb + (size_t)(row * Ww + col) * Cc + c4);
        unsigned addr = (unsigned)pxl * (Cc * KK * 2)
                      + ((((unsigned)(kk * 64 + c4)) * 2) ^ ((unsigned)(pxl & 7) << 4));
        *(ushort4*)(s_buf + addr) = u;
    }
    __syncthreads();

    // ---- P0-MFMA (waves 0..3): offsets[32px][18oc] = taps @ Woff^T
    if (wv < 4) {
        const int oto = wv >> 1, pxt = wv & 1;
        const unsigned swz = (unsigned)(lane & 7) << 4;
        const unsigned rA = ((unsigned)(lane & 15) + (unsigned)pxt * 16) * (Cc * KK * 2);
        f32x4 a = {0.f, 0.f, 0.f, 0.f};
        const bf16x8* Bo = (const bf16x8*)Fo + (size_t)oto * KSD * 64;
        #pragma unroll 3
        for (int ks = 0; ks < KSD; ++ks) {
            unsigned cb = ((unsigned)(ks * 64 + klane * 16)) ^ swz;
            bf16x8 af = *(const bf16x8*)(s_buf + rA + cb);
            a = __builtin_amdgcn_mfma_f32_16x16x32_bf16(af, Bo[ks * 64 + lane], a, 0, 0, 0);
        }
        int oc = oto * 16 + (lane & 15);
        if (oc < OFFC) {
            float bv = boff[oc];
            #pragma unroll
            for (int r = 0; r < 4; ++r)
                s_off[pxt * 16 + klane * 4 + r][oc] = a[r] + bv;
        }
    }
    __syncthreads();

    // ---- P1a: bilinear params once per (tap,pixel) item -> s_pp
    if (t < NIT) {
        int i = t;
        int kk = i >> 5, pxl = i & 31;
        int ky = (kk * 11) >> 5, kx = kk - ky * 3;
        float py  = s_off[pxl][kk * 2]     + (float)(h - 1 + ky);
        float pxf = s_off[pxl][kk * 2 + 1] + (float)(w0 + pxl - 1 + kx);
        float fy0 = floorf(py), fx0 = floorf(pxf);
        float wy = py - fy0, wx = pxf - fx0;
        int iy0 = (int)fy0, ix0 = (int)fx0, iy1 = iy0 + 1, ix1 = ix0 + 1;
        float v00 = (iy0 >= 0 && iy0 < Hh && ix0 >= 0 && ix0 < Ww) ? 1.f : 0.f;
        float v01 = (iy0 >= 0 && iy0 < Hh && ix1 >= 0 && ix1 < Ww) ? 1.f : 0.f;
        float v10 = (iy1 >= 0 && iy1 < Hh && ix0 >= 0 && ix0 < Ww) ? 1.f : 0.f;
        float v11 = (iy1 >= 0 && iy1 < Hh && ix1 >= 0 && ix1 < Ww) ? 1.f : 0.f;
        int cy0 = min(max(iy0, 0), Hh - 1), cy1 = min(max(iy1, 0), Hh - 1);
        int cx0 = min(max(ix0, 0), Ww - 1), cx1 = min(max(ix1, 0), Ww - 1);
        int* pp = &s_pp[i * 8];
        pp[0] = (cy0 * Ww + cx0) * (Cc * 2);       // byte offsets, pre-multiplied
        pp[1] = (cy0 * Ww + cx1) * (Cc * 2);
        pp[2] = (cy1 * Ww + cx0) * (Cc * 2);
        pp[3] = (cy1 * Ww + cx1) * (Cc * 2);
        pp[4] = __float_as_int((1.f - wy) * (1.f - wx) * v00);
        pp[5] = __float_as_int((1.f - wy) * wx * v01);
        pp[6] = __float_as_int(wy * (1.f - wx) * v10);
        pp[7] = __float_as_int(wy * wx * v11);
    }
    __syncthreads();

    // ---- P1b: vectorized bilinear gather -> s_buf overwrite (4 ch per lane)
    const unsigned char* xbB = (const unsigned char*)xb + (size_t)c4 * 2;
    #pragma unroll 3
    for (int it = 0; it < NIT / 32; ++it) {
        int item = it * 32 + wv * 4 + klane;
        int kk = item >> 5, pxl = item & 31;
        const int* pp = &s_pp[item * 8];
        int4   idx = *(const int4*)pp;             // broadcast within 16-lane group
        float4 wt  = *(const float4*)(pp + 4);
        ushort4 u00 = *(const ushort4*)(xbB + idx.x);
        ushort4 u01 = *(const ushort4*)(xbB + idx.y);
        ushort4 u10 = *(const ushort4*)(xbB + idx.z);
        ushort4 u11 = *(const ushort4*)(xbB + idx.w);
        float v0 = wt.x * bf2f(u00.x) + wt.y * bf2f(u01.x) + wt.z * bf2f(u10.x) + wt.w * bf2f(u11.x);
        float v1 = wt.x * bf2f(u00.y) + wt.y * bf2f(u01.y) + wt.z * bf2f(u10.y) + wt.w * bf2f(u11.y);
        float v2 = wt.x * bf2f(u00.z) + wt.y * bf2f(u01.z) + wt.z * bf2f(u10.z) + wt.w * bf2f(u11.z);
        float v3 = wt.x * bf2f(u00.w) + wt.y * bf2f(u01.w) + wt.z * bf2f(u10.w) + wt.w * bf2f(u11.w);
        ushort4 o4;
        o4.x = f2bf(v0); o4.y = f2bf(v1); o4.z = f2bf(v2); o4.w = f2bf(v3);
        unsigned addr = (unsigned)pxl * (Cc * KK * 2)
                      + ((((unsigned)(kk * 64 + c4)) * 2) ^ ((unsigned)(pxl & 7) << 4));
        *(ushort4*)(s_buf + addr) = o4;
    }
    __syncthreads();

    // ---- P2: deform GEMM  y1[32px][64o] = samp @ Wdef^T ; wave -> (ot = wv>>1, pxt = wv&1)
    const int ot = wv >> 1, pxt = wv & 1;
    const unsigned swzA = (unsigned)(lane & 7) << 4;
    const unsigned rA = ((unsigned)(lane & 15) + (unsigned)pxt * 16) * (Cc * KK * 2);
    f32x4 acc = {0.f, 0.f, 0.f, 0.f};
    const bf16x8* Bd = (const bf16x8*)Fd + (size_t)ot * KSD * 64;
    #pragma unroll 3
    for (int ks = 0; ks < KSD; ++ks) {
        unsigned cb = ((unsigned)(ks * 64 + klane * 16)) ^ swzA;
        bf16x8 a0 = *(const bf16x8*)(s_buf + rA + cb);
        bf16x8 bd = Bd[ks * 64 + lane];
        acc = __builtin_amdgcn_mfma_f32_16x16x32_bf16(a0, bd, acc, 0, 0, 0);
    }
    const int o = ot * 16 + (lane & 15);
    {
        float bv = bdef[o];
        unsigned colb = (unsigned)o * 2;
        #pragma unroll
        for (int r = 0; r < 4; ++r) {
            int row = pxt * 16 + klane * 4 + r;
            unsigned sw = (unsigned)((klane * 4 + r) & 7) << 4;   // == (row&7)<<4
            *(unsigned short*)(s_y1 + row * (Cc * 2) + (colb ^ sw)) = f2bf(acc[r] + bv);
        }
    }
    __syncthreads();

    // ---- P3: 1x1 GEMM  yout[32px][64o] = y1 @ Wcat^T
    f32x4 cacc = {0.f, 0.f, 0.f, 0.f};
    const bf16x8* Bc = (const bf16x8*)Fc + (size_t)ot * KSC * 64;
    const unsigned rY = ((unsigned)(lane & 15) + (unsigned)pxt * 16) * (Cc * 2);
    #pragma unroll
    for (int ks = 0; ks < KSC; ++ks) {
        unsigned cb = ((unsigned)(ks * 64 + klane * 16)) ^ swzA;
        bf16x8 a0 = *(const bf16x8*)(s_y1 + rY + cb);
        bf16x8 bc = Bc[ks * 64 + lane];
        cacc = __builtin_amdgcn_mfma_f32_16x16x32_bf16(a0, bc, cacc, 0, 0, 0);
    }

    // ---- BN partial stats from registers (this wave's 16 px; pxt pair covers 32)
    float vals[4];
    {
        float bcv = bcat[o];
        #pragma unroll
        for (int r = 0; r < 4; ++r) vals[r] = cacc[r] + bcv;
        float s1 = 0.f, s2 = 0.f;
        #pragma unroll
        for (int j = 0; j < 4; ++j) { s1 += vals[j]; s2 += vals[j] * vals[j]; }
        s1 += __shfl_xor(s1, 16); s1 += __shfl_xor(s1, 32);
        s2 += __shfl_xor(s2, 16); s2 += __shfl_xor(s2, 32);
        if (klane == 0) {
            atomicAdd(&psum[o * SLOTS + slot], s1);
            atomicAdd(&psum[Cc * SLOTS + o * SLOTS + slot], s2);
        }
    }

    // ---- Epilogue: transpose via LDS (aliases s_buf) -> coalesced bf16 stores
    __syncthreads();     // all s_buf readers (P2) are past the s_y1 barrier; fence before overwrite
    {
        unsigned orow = (unsigned)o * (PXB * 4);
        unsigned sw   = (unsigned)(o & 7) << 4;
        #pragma unroll
        for (int r = 0; r < 4; ++r) {
            int p = pxt * 16 + klane * 4 + r;
            *(float*)(s_buf + orow + (((unsigned)p * 4) ^ sw)) = vals[r];
        }
    }
    __syncthreads();
    unsigned short* yb = y + (size_t)b * Cc * HWp + px0;
    {
        int oo = t >> 3, pxq = t & 7;              // 512 threads cover 64 x 8
        float4 v = *(const float4*)(s_buf + (unsigned)oo * (PXB * 4)
                                    + (((unsigned)pxq * 16) ^ ((unsigned)(oo & 7) << 4)));
        ushort4 u;
        u.x = f2bf(v.x); u.y = f2bf(v.y); u.z = f2bf(v.z); u.w = f2bf(v.w);
        *(ushort4*)(yb + (size_t)oo * HWp + pxq * 4) = u;
    }
}

// ---------------- Kernel 3: combine slotted partials -> mean/invstd ----------------
__global__ __launch_bounds__(64)
void k_stats_final(const float* __restrict__ psum, float* __restrict__ stats) {
    int c = threadIdx.x;              // 64 threads
    double t1 = 0.0, t2 = 0.0;
    for (int s = 0; s < SLOTS; ++s) {
        t1 += (double)psum[c * SLOTS + s];
        t2 += (double)psum[Cc * SLOTS + c * SLOTS + s];
    }
    double n = (double)(Bb * HWp);
    double mean = t1 / n;
    double var  = t2 / n - mean * mean;
    stats[c]      = (float)mean;
    stats[Cc + c] = (float)(1.0 / sqrt(var + 1e-5));
}

// ---------------- Kernel 4: BN apply + ReLU + residual (bf16 y in, f32 out) ----------------
__global__ __launch_bounds__(256)
void k_apply(const unsigned short* __restrict__ y, const float4* __restrict__ x,
             const float* __restrict__ stats, const float* __restrict__ gamma,
             const float* __restrict__ beta, float4* __restrict__ out) {
    int idx = blockIdx.x * 256 + threadIdx.x;           // over B*C*HW/4
    int c = (idx / (HWp / 4)) % Cc;
    float mean = stats[c], inv = stats[Cc + c];
    float g = gamma[c], bt = beta[c];
    ushort4 yv = *(const ushort4*)(y + (size_t)idx * 4);
    float4 xv = x[idx], o;
    o.x = fmaxf(g * ((bf2f(yv.x) - mean) * inv) + bt, 0.f) + xv.x;
    o.y = fmaxf(g * ((bf2f(yv.y) - mean) * inv) + bt, 0.f) + xv.y;
    o.z = fmaxf(g * ((bf2f(yv.z) - mean) * inv) + bt, 0.f) + xv.z;
    o.w = fmaxf(g * ((bf2f(yv.w) - mean) * inv) + bt, 0.f) + xv.w;
    out[idx] = o;
}

extern "C" void kernel_launch(void* const* d_in, const int* in_sizes, int n_in,
                              void* d_out, int out_size, void* d_ws, size_t ws_size,
                              hipStream_t stream) {
    const float* x     = (const float*)d_in[0];
    const float* Woff  = (const float*)d_in[1];
    const float* boff  = (const float*)d_in[2];
    const float* Wdef  = (const float*)d_in[3];
    const float* bdef  = (const float*)d_in[4];
    const float* Wcat  = (const float*)d_in[5];
    const float* bcat  = (const float*)d_in[6];
    const float* gamma = (const float*)d_in[7];
    const float* beta  = (const float*)d_in[8];
    float* out = (float*)d_out;

    float* ws    = (float*)d_ws;
    float* stats = ws;                                  // 128 f32
    float* psum  = stats + 128;                         // 2*64*SLOTS = 8192 f32
    unsigned short* y16 = (unsigned short*)(psum + 2 * Cc * SLOTS);  // 9,437,184 u16 (16B-aligned)
    unsigned short* Fd  = y16 + (size_t)Bb * Cc * HWp;   // 36,864 u16
    unsigned short* Fc  = Fd + 4 * KSD * 64 * 8;         // 4,096 u16
    unsigned short* Fo  = Fc + 4 * KSC * 64 * 8;         // 18,432 u16
    unsigned short* xcl = Fo + 2 * KSD * 64 * 8;         // 9,437,184 u16

    k_prep<<<dim3(NXP + NWP + NZP), dim3(256), 0, stream>>>(x, Wdef, Wcat, Woff,
                                                            xcl, Fd, Fc, Fo, psum);
    k_fused<<<dim3(Bb * NBPX), dim3(512), 0, stream>>>(xcl, Fo, boff, Fd, bdef, Fc, bcat, y16, psum);
    k_stats_final<<<dim3(1), dim3(64), 0, stream>>>(psum, stats);
    k_apply<<<dim3(Bb * Cc * HWp / 4 / 256), dim3(256), 0, stream>>>(
        y16, (const float4*)x, stats, gamma, beta, (float4*)out);
}

// Round 9
// 207.193 us; speedup vs baseline: 1.0710x; 1.0710x over previous
//
#include <hip/hip_runtime.h>
#include <math.h>

// Problem constants (B=4, C=64, H=W=192, K=3)
constexpr int Hh  = 192;
constexpr int Ww  = 192;
constexpr int HWp = Hh * Ww;      // 36864
constexpr int Cc  = 64;
constexpr int Bb  = 4;
constexpr int KK  = 9;
constexpr int OFFC = 18;          // 2*K*K
constexpr int PXB = 32;           // pixels per fused block (divides Ww)
constexpr int NBPX = HWp / PXB;   // 1152 tiles per batch image
constexpr int KSD = (Cc * KK) / 32;  // 18 K-steps, K=576
constexpr int KSC = Cc / 32;         // 2  K-steps, K=64
constexpr int NIT = KK * PXB;        // 288 (tap,pixel) items per block
constexpr int SLOTS = 64;            // stats accumulation slots per channel
constexpr int XT_COLS = PXB + 2;     // 34 unique x columns for the 3x3 tap window
constexpr int XT_ITEMS = 3 * XT_COLS;// 102 unique (row,col) x-tile items

constexpr int NXP = Bb * (HWp / 64);                                 // 2304 xpose blocks
constexpr int NWP = (4 * KSD * 64 * 8 + 4 * KSC * 64 * 8 + 2 * KSD * 64 * 8) / 256;  // 232
constexpr int NZP = (2 * Cc * SLOTS / 4) / 256;                      // 8 psum-zero blocks

using bf16x8 = __attribute__((ext_vector_type(8))) short;  // 8 bf16 (4 VGPRs)
using f32x4  = __attribute__((ext_vector_type(4))) float;
using f32x2  = __attribute__((ext_vector_type(2))) float;  // -> v_pk_* on CDNA

static __device__ __forceinline__ unsigned short f2bf(float f) {
    unsigned int u = __float_as_uint(f);
    u += 0x7fff + ((u >> 16) & 1);       // round-to-nearest-even
    return (unsigned short)(u >> 16);
}
static __device__ __forceinline__ float bf2f(unsigned short u) {
    return __uint_as_float((unsigned)u << 16);
}

// ---------------- Kernel 1: prep = {x transpose to CL bf16 | weight packing | psum zero} --------
// B-frag (16x16x32): lane l, reg r holds B[k = ks*32 + (l>>4)*8 + r][n = ot*16 + (l&15)]
// Deform/offset K-ordering is kk-major: ck2 = kk*64 + c (matches samp tile layout).
__global__ __launch_bounds__(256)
void k_prep(const float* __restrict__ x, const float* __restrict__ Wdef,
            const float* __restrict__ Wcat, const float* __restrict__ Woff,
            unsigned short* __restrict__ xcl, unsigned short* __restrict__ Fd,
            unsigned short* __restrict__ Fc, unsigned short* __restrict__ Fo,
            float* __restrict__ psum) {
    __shared__ unsigned int wtile[64][32];     // u32 = 2 px of one channel; XOR-swizzled words
    const int bid = blockIdx.x;
    const int t = threadIdx.x;
    if (bid < NXP) {
        // ---- x NCHW f32 -> channels-last bf16 [B][HW][64c], conflict-free XOR transpose
        int b   = bid / (HWp / 64);
        int px0 = (bid % (HWp / 64)) * 64;
        #pragma unroll
        for (int r = 0; r < 4; ++r) {                  // write: 16 lanes share channel row
            int cc = r * 16 + (t >> 4), px4 = (t & 15) * 4;
            float4 v = *(const float4*)(x + ((size_t)b * Cc + cc) * HWp + px0 + px4);
            unsigned lo  = (unsigned)f2bf(v.x) | ((unsigned)f2bf(v.y) << 16);
            unsigned hi2 = (unsigned)f2bf(v.z) | ((unsigned)f2bf(v.w) << 16);
            unsigned e = (unsigned)(cc & 31);
            wtile[cc][((unsigned)(px4 >> 1)    ) ^ e] = lo;
            wtile[cc][((unsigned)(px4 >> 1) + 1) ^ e] = hi2;
        }
        __syncthreads();
        #pragma unroll
        for (int r = 0; r < 4; ++r) {                  // read: lanes span channels (swizzled banks)
            int pxl = r * 16 + (t >> 4), c4l = (t & 15) * 4;
            int hsel = (pxl & 1) * 16;
            unsigned w0 = wtile[c4l + 0][(unsigned)(pxl >> 1) ^ (unsigned)((c4l + 0) & 31)];
            unsigned w1 = wtile[c4l + 1][(unsigned)(pxl >> 1) ^ (unsigned)((c4l + 1) & 31)];
            unsigned w2 = wtile[c4l + 2][(unsigned)(pxl >> 1) ^ (unsigned)((c4l + 2) & 31)];
            unsigned w3 = wtile[c4l + 3][(unsigned)(pxl >> 1) ^ (unsigned)((c4l + 3) & 31)];
            ushort4 u;
            u.x = (unsigned short)(w0 >> hsel);
            u.y = (unsigned short)(w1 >> hsel);
            u.z = (unsigned short)(w2 >> hsel);
            u.w = (unsigned short)(w3 >> hsel);
            *(ushort4*)(xcl + ((size_t)b * HWp + px0 + pxl) * Cc + c4l) = u;
        }
    } else if (bid < NXP + NWP) {
        int i = (bid - NXP) * 256 + t;
        if (i < 4 * KSD * 64 * 8) {                    // Fd: [ot4][ks18][lane][r]
            int r = i & 7, lane = (i >> 3) & 63, ks = (i >> 9) % KSD, ot = (i >> 9) / KSD;
            int o  = ot * 16 + (lane & 15);
            int kp = ks * 32 + ((lane >> 4) << 3) + r; // ck2 = kk*64 + c
            int kk = kp >> 6, c = kp & 63;
            Fd[i] = f2bf(Wdef[o * (Cc * KK) + c * KK + kk]);
        }
        int j = i - 4 * KSD * 64 * 8;
        if (j >= 0 && j < 4 * KSC * 64 * 8) {          // Fc: [ot4][ks2][lane][r]  (K = c)
            int r = j & 7, lane = (j >> 3) & 63, ks = (j >> 9) & 1, ot = j >> 10;
            int o = ot * 16 + (lane & 15);
            int c = ks * 32 + ((lane >> 4) << 3) + r;
            Fc[j] = f2bf(Wcat[o * Cc + c]);
        }
        int m = j - 4 * KSC * 64 * 8;
        if (m >= 0 && m < 2 * KSD * 64 * 8) {          // Fo: [ot2][ks18][lane][r], oc>=18 zero
            int r = m & 7, lane = (m >> 3) & 63, ks = (m >> 9) % KSD, ot = (m >> 9) / KSD;
            int o  = ot * 16 + (lane & 15);
            int kp = ks * 32 + ((lane >> 4) << 3) + r;
            int kk = kp >> 6, c = kp & 63;
            Fo[m] = (o < OFFC) ? f2bf(Woff[o * (Cc * KK) + c * KK + kk]) : 0;
        }
    } else {
        int j = (bid - NXP - NWP) * 256 + t;           // zero psum: 2048 float4
        float4 z = {0.f, 0.f, 0.f, 0.f};
        ((float4*)psum)[j] = z;
    }
}

// ---------------- Kernel 2: FUSED offset-conv + deformable conv + 1x1 conv + BN partials --------
// 256 threads (4 waves), 3 blocks/CU (LDS-limited).
__global__ __launch_bounds__(256, 3)
void k_fused(const unsigned short* __restrict__ xcl,
             const unsigned short* __restrict__ Fo, const float* __restrict__ boff,
             const unsigned short* __restrict__ Fd, const float* __restrict__ bdef,
             const unsigned short* __restrict__ Fc, const float* __restrict__ bcat,
             unsigned short* __restrict__ y, float* __restrict__ psum) {
    // s_buf: (a) x-tile [102 rows][64 ch] bf16 for P0; (b) samp bf16 [32 px][576 ck2] for P2;
    //        (c) fp32 [64 o][32 px] in epilogue.  All XOR-swizzled, phase-aliased.
    __shared__ __align__(16) unsigned char s_buf[PXB * Cc * KK * 2];   // 36864 B
    __shared__ __align__(16) unsigned char s_y1[PXB * Cc * 2];         // 4096 B
    __shared__ float s_off[PXB][OFFC];                                 // 2304 B
    __shared__ __align__(16) int s_pp[NIT * 8];                        // 9216 B

    const int t = threadIdx.x;
    const int lane = t & 63, wv = t >> 6;          // 4 waves
    const int klane = (lane >> 4) & 3;
    const int c4 = (lane & 15) * 4;
    int wg = blockIdx.x;
    const int slot = wg & (SLOTS - 1);
    wg = (wg & 7) * (Bb * NBPX / 8) + (wg >> 3);   // XCD swizzle (4608 % 8 == 0 -> bijective)
    const int b   = wg / NBPX;
    const int px0 = (wg % NBPX) * PXB;
    const int h   = px0 / Ww;                      // uniform: PXB divides Ww
    const int w0  = px0 % Ww;
    const unsigned short* xb = xcl + (size_t)b * HWp * Cc;

    // ---- P0: compact x-tile stage: 3 rows x 34 cols x 64 ch (102 items, each 128B)
    #pragma unroll
    for (int it = 0; it < 7; ++it) {
        int item = it * 16 + wv * 4 + klane;       // 0..111
        if (item < XT_ITEMS) {
            int ry = item / XT_COLS, cx = item - ry * XT_COLS;
            int row = h + ry - 1, col = w0 + cx - 1;
            ushort4 u = {0, 0, 0, 0};
            if (row >= 0 && row < Hh && col >= 0 && col < Ww)
                u = *(const ushort4*)(xb + (size_t)(row * Ww + col) * Cc + c4);
            unsigned addr = (unsigned)item * 128
                          + (((unsigned)c4 * 2) ^ (((unsigned)item & 7) << 4));
            *(ushort4*)(s_buf + addr) = u;
        }
    }
    __syncthreads();

    // ---- P0-MFMA: offsets[32px][18oc] = taps @ Woff^T, A read straight from x-tile
    {
        const int oto = wv >> 1, pxt0 = wv & 1;
        const int pxv = (lane & 15) + pxt0 * 16;
        f32x4 a = {0.f, 0.f, 0.f, 0.f};
        const bf16x8* Bo = (const bf16x8*)Fo + (size_t)oto * KSD * 64;
        #pragma unroll
        for (int ks = 0; ks < KSD; ++ks) {
            const int kk = ks >> 1;                // compile-time per unrolled iter
            const int ky = kk / 3, kx = kk % 3;
            int row_l = ky * XT_COLS + pxv + kx;
            unsigned c0b = (unsigned)(((ks & 1) * 32 + klane * 8) * 2);
            unsigned addr = (unsigned)row_l * 128 + (c0b ^ (((unsigned)row_l & 7) << 4));
            bf16x8 af = *(const bf16x8*)(s_buf + addr);
            a = __builtin_amdgcn_mfma_f32_16x16x32_bf16(af, Bo[ks * 64 + lane], a, 0, 0, 0);
        }
        int oc = oto * 16 + (lane & 15);
        if (oc < OFFC) {
            float bv = boff[oc];
            #pragma unroll
            for (int r = 0; r < 4; ++r)
                s_off[pxt0 * 16 + klane * 4 + r][oc] = a[r] + bv;
        }
    }
    __syncthreads();

    // ---- P1a: bilinear params once per (tap,pixel) item -> s_pp
    for (int i = t; i < NIT; i += 256) {
        int kk = i >> 5, pxl = i & 31;
        int ky = (kk * 11) >> 5, kx = kk - ky * 3;
        float py  = s_off[pxl][kk * 2]     + (float)(h - 1 + ky);
        float pxf = s_off[pxl][kk * 2 + 1] + (float)(w0 + pxl - 1 + kx);
        float fy0 = floorf(py), fx0 = floorf(pxf);
        float wy = py - fy0, wx = pxf - fx0;
        int iy0 = (int)fy0, ix0 = (int)fx0, iy1 = iy0 + 1, ix1 = ix0 + 1;
        float v00 = (iy0 >= 0 && iy0 < Hh && ix0 >= 0 && ix0 < Ww) ? 1.f : 0.f;
        float v01 = (iy0 >= 0 && iy0 < Hh && ix1 >= 0 && ix1 < Ww) ? 1.f : 0.f;
        float v10 = (iy1 >= 0 && iy1 < Hh && ix0 >= 0 && ix0 < Ww) ? 1.f : 0.f;
        float v11 = (iy1 >= 0 && iy1 < Hh && ix1 >= 0 && ix1 < Ww) ? 1.f : 0.f;
        int cy0 = min(max(iy0, 0), Hh - 1), cy1 = min(max(iy1, 0), Hh - 1);
        int cx0 = min(max(ix0, 0), Ww - 1), cx1 = min(max(ix1, 0), Ww - 1);
        int* pp = &s_pp[i * 8];
        pp[0] = (cy0 * Ww + cx0) * (Cc * 2);       // byte offsets, pre-multiplied
        pp[1] = (cy0 * Ww + cx1) * (Cc * 2);
        pp[2] = (cy1 * Ww + cx0) * (Cc * 2);
        pp[3] = (cy1 * Ww + cx1) * (Cc * 2);
        pp[4] = __float_as_int((1.f - wy) * (1.f - wx) * v00);
        pp[5] = __float_as_int((1.f - wy) * wx * v01);
        pp[6] = __float_as_int(wy * (1.f - wx) * v10);
        pp[7] = __float_as_int(wy * wx * v11);
    }
    __syncthreads();

    // ---- P1b: vectorized bilinear gather -> s_buf overwrite (4 ch/lane, packed-f32 math)
    const unsigned char* xbB = (const unsigned char*)xb + (size_t)c4 * 2;
    #pragma unroll 6
    for (int it = 0; it < NIT / 16; ++it) {
        int item = it * 16 + wv * 4 + klane;
        int kk = item >> 5, pxl = item & 31;
        const int* pp = &s_pp[item * 8];
        int4   idx = *(const int4*)pp;             // broadcast within 16-lane group
        float4 wt  = *(const float4*)(pp + 4);
        ushort4 u00 = *(const ushort4*)(xbB + idx.x);
        ushort4 u01 = *(const ushort4*)(xbB + idx.y);
        ushort4 u10 = *(const ushort4*)(xbB + idx.z);
        ushort4 u11 = *(const ushort4*)(xbB + idx.w);
        f32x2 lo00 = {bf2f(u00.x), bf2f(u00.y)}, hi00 = {bf2f(u00.z), bf2f(u00.w)};
        f32x2 lo01 = {bf2f(u01.x), bf2f(u01.y)}, hi01 = {bf2f(u01.z), bf2f(u01.w)};
        f32x2 lo10 = {bf2f(u10.x), bf2f(u10.y)}, hi10 = {bf2f(u10.z), bf2f(u10.w)};
        f32x2 lo11 = {bf2f(u11.x), bf2f(u11.y)}, hi11 = {bf2f(u11.z), bf2f(u11.w)};
        f32x2 vlo = wt.x * lo00 + wt.y * lo01 + wt.z * lo10 + wt.w * lo11;
        f32x2 vhi = wt.x * hi00 + wt.y * hi01 + wt.z * hi10 + wt.w * hi11;
        ushort4 o4;
        o4.x = f2bf(vlo[0]); o4.y = f2bf(vlo[1]); o4.z = f2bf(vhi[0]); o4.w = f2bf(vhi[1]);
        unsigned addr = (unsigned)pxl * (Cc * KK * 2)
                      + ((((unsigned)(kk * 64 + c4)) * 2) ^ ((unsigned)(pxl & 7) << 4));
        *(ushort4*)(s_buf + addr) = o4;
    }
    __syncthreads();

    // ---- P2: deform GEMM  y1[32px][64o] = samp @ Wdef^T ; wave -> oc tile, both px tiles
    const int ot = wv;
    const unsigned swzA = (unsigned)(lane & 7) << 4;
    const unsigned rA0  = (unsigned)(lane & 15) * (Cc * KK * 2);
    const unsigned rA1  = rA0 + 16u * (Cc * KK * 2);
    f32x4 acc0 = {0.f, 0.f, 0.f, 0.f}, acc1 = {0.f, 0.f, 0.f, 0.f};
    const bf16x8* Bd = (const bf16x8*)Fd + (size_t)ot * KSD * 64;
    #pragma unroll 3
    for (int ks = 0; ks < KSD; ++ks) {
        unsigned cb = ((unsigned)(ks * 64 + klane * 16)) ^ swzA;
        bf16x8 a0 = *(const bf16x8*)(s_buf + rA0 + cb);
        bf16x8 a1 = *(const bf16x8*)(s_buf + rA1 + cb);
        bf16x8 bd = Bd[ks * 64 + lane];
        acc0 = __builtin_amdgcn_mfma_f32_16x16x32_bf16(a0, bd, acc0, 0, 0, 0);
        acc1 = __builtin_amdgcn_mfma_f32_16x16x32_bf16(a1, bd, acc1, 0, 0, 0);
    }
    const int o = ot * 16 + (lane & 15);
    {
        float bv = bdef[o];
        unsigned colb = (unsigned)o * 2;
        #pragma unroll
        for (int r = 0; r < 4; ++r) {
            int row0 = klane * 4 + r, row1 = row0 + 16;
            unsigned sw = (unsigned)(row0 & 7) << 4;
            *(unsigned short*)(s_y1 + row0 * (Cc * 2) + (colb ^ sw)) = f2bf(acc0[r] + bv);
            *(unsigned short*)(s_y1 + row1 * (Cc * 2) + (colb ^ sw)) = f2bf(acc1[r] + bv);
        }
    }
    __syncthreads();

    // ---- P3: 1x1 GEMM  yout[32px][64o] = y1 @ Wcat^T
    f32x4 c0 = {0.f, 0.f, 0.f, 0.f}, c1 = {0.f, 0.f, 0.f, 0.f};
    const bf16x8* Bc = (const bf16x8*)Fc + (size_t)ot * KSC * 64;
    const unsigned rY0 = (unsigned)(lane & 15) * (Cc * 2);
    const unsigned rY1 = rY0 + 16u * (Cc * 2);
    #pragma unroll
    for (int ks = 0; ks < KSC; ++ks) {
        unsigned cb = ((unsigned)(ks * 64 + klane * 16)) ^ swzA;
        bf16x8 a0 = *(const bf16x8*)(s_y1 + rY0 + cb);
        bf16x8 a1 = *(const bf16x8*)(s_y1 + rY1 + cb);
        bf16x8 bc = Bc[ks * 64 + lane];
        c0 = __builtin_amdgcn_mfma_f32_16x16x32_bf16(a0, bc, c0, 0, 0, 0);
        c1 = __builtin_amdgcn_mfma_f32_16x16x32_bf16(a1, bc, c1, 0, 0, 0);
    }

    // ---- BN partial stats from registers: per-channel sum / sumsq over this block's 32 px
    float vals[8];
    {
        float bcv = bcat[o];
        #pragma unroll
        for (int r = 0; r < 4; ++r) { vals[r] = c0[r] + bcv; vals[4 + r] = c1[r] + bcv; }
        float s1 = 0.f, s2 = 0.f;
        #pragma unroll
        for (int j = 0; j < 8; ++j) { s1 += vals[j]; s2 += vals[j] * vals[j]; }
        s1 += __shfl_xor(s1, 16); s1 += __shfl_xor(s1, 32);
        s2 += __shfl_xor(s2, 16); s2 += __shfl_xor(s2, 32);
        if (klane == 0) {
            atomicAdd(&psum[o * SLOTS + slot], s1);
            atomicAdd(&psum[Cc * SLOTS + o * SLOTS + slot], s2);
        }
    }

    // ---- Epilogue: transpose via LDS (aliases s_buf) -> coalesced bf16 stores
    __syncthreads();     // all s_buf readers (P2) are past the s_y1 barrier; fence before overwrite
    {
        unsigned orow = (unsigned)o * (PXB * 4);
        unsigned sw   = (unsigned)(o & 7) << 4;
        #pragma unroll
        for (int r = 0; r < 4; ++r) {
            int p0 = klane * 4 + r, p1 = p0 + 16;
            *(float*)(s_buf + orow + (((unsigned)p0 * 4) ^ sw)) = vals[r];
            *(float*)(s_buf + orow + (((unsigned)p1 * 4) ^ sw)) = vals[4 + r];
        }
    }
    __syncthreads();
    unsigned short* yb = y + (size_t)b * Cc * HWp + px0;
    #pragma unroll
    for (int it = 0; it < 2; ++it) {
        int oo = it * 32 + (t >> 3), pxq = t & 7;
        float4 v = *(const float4*)(s_buf + (unsigned)oo * (PXB * 4)
                                    + (((unsigned)pxq * 16) ^ ((unsigned)(oo & 7) << 4)));
        ushort4 u;
        u.x = f2bf(v.x); u.y = f2bf(v.y); u.z = f2bf(v.z); u.w = f2bf(v.w);
        *(ushort4*)(yb + (size_t)oo * HWp + pxq * 4) = u;
    }
}

// ---------------- Kernel 3: BN finalize (per-block slot reduce) + apply + ReLU + residual -------
__global__ __launch_bounds__(256)
void k_apply(const unsigned short* __restrict__ y, const float4* __restrict__ x,
             const float* __restrict__ psum, const float* __restrict__ gamma,
             const float* __restrict__ beta, float4* __restrict__ out) {
    __shared__ float smv[2];
    const int t = threadIdx.x;
    const int idx = blockIdx.x * 256 + t;               // float4 units over B*C*HW/4
    const int c = (blockIdx.x * 1024 / HWp) % Cc;       // uniform: 36 blocks per (b,c) row
    if (t < 64) {
        float s1 = psum[c * SLOTS + t];
        float s2 = psum[Cc * SLOTS + c * SLOTS + t];
        #pragma unroll
        for (int d = 1; d < 64; d <<= 1) {
            s1 += __shfl_xor(s1, d);
            s2 += __shfl_xor(s2, d);
        }
        if (t == 0) {
            float n = (float)(Bb * HWp);
            float mean = s1 / n;
            float var  = s2 / n - mean * mean;
            smv[0] = mean;
            smv[1] = 1.0f / sqrtf(var + 1e-5f);
        }
    }
    __syncthreads();
    float mean = smv[0], inv = smv[1];
    float g = gamma[c], bt = beta[c];
    ushort4 yv = *(const ushort4*)(y + (size_t)idx * 4);
    float4 xv = x[idx], o;
    o.x = fmaxf(g * ((bf2f(yv.x) - mean) * inv) + bt, 0.f) + xv.x;
    o.y = fmaxf(g * ((bf2f(yv.y) - mean) * inv) + bt, 0.f) + xv.y;
    o.z = fmaxf(g * ((bf2f(yv.z) - mean) * inv) + bt, 0.f) + xv.z;
    o.w = fmaxf(g * ((bf2f(yv.w) - mean) * inv) + bt, 0.f) + xv.w;
    out[idx] = o;
}

extern "C" void kernel_launch(void* const* d_in, const int* in_sizes, int n_in,
                              void* d_out, int out_size, void* d_ws, size_t ws_size,
                              hipStream_t stream) {
    const float* x     = (const float*)d_in[0];
    const float* Woff  = (const float*)d_in[1];
    const float* boff  = (const float*)d_in[2];
    const float* Wdef  = (const float*)d_in[3];
    const float* bdef  = (const float*)d_in[4];
    const float* Wcat  = (const float*)d_in[5];
    const float* bcat  = (const float*)d_in[6];
    const float* gamma = (const float*)d_in[7];
    const float* beta  = (const float*)d_in[8];
    float* out = (float*)d_out;

    float* ws    = (float*)d_ws;
    float* psum  = ws;                                   // 2*64*SLOTS = 8192 f32
    unsigned short* y16 = (unsigned short*)(psum + 2 * Cc * SLOTS);  // 9,437,184 u16 (16B-aligned)
    unsigned short* Fd  = y16 + (size_t)Bb * Cc * HWp;   // 36,864 u16
    unsigned short* Fc  = Fd + 4 * KSD * 64 * 8;         // 4,096 u16
    unsigned short* Fo  = Fc + 4 * KSC * 64 * 8;         // 18,432 u16
    unsigned short* xcl = Fo + 2 * KSD * 64 * 8;         // 9,437,184 u16

    k_prep<<<dim3(NXP + NWP + NZP), dim3(256), 0, stream>>>(x, Wdef, Wcat, Woff,
                                                            xcl, Fd, Fc, Fo, psum);
    k_fused<<<dim3(Bb * NBPX), dim3(256), 0, stream>>>(xcl, Fo, boff, Fd, bdef, Fc, bcat, y16, psum);
    k_apply<<<dim3(Bb * Cc * HWp / 4 / 256), dim3(256), 0, stream>>>(
        y16, (const float4*)x, psum, gamma, beta, (float4*)out);
}